// Round 6
// baseline (1197.866 us; speedup 1.0000x reference)
//
#include <hip/hip_runtime.h>
#include <math.h>

// Problem constants
#define BB 8
#define NN 4096
#define CC 96
#define C2 192
#define NP 1024
#define NS 16
#define FPT 8    // points per thread in FPS (512 threads * 8 = 4096)

// ws layout (bytes)
#define SAMP_OFF   0u           // int[8*1024]            32768
#define NBR_OFF    32768u       // int[8*1024*16]        524288
#define WSW_OFF    655360u      // float[384*96]         147456
#define B1_OFF     802816u      // float[192]               768
#define WCT_OFF    803584u      // float[192*192]        147456
#define B2_OFF     951040u      // float[192]               768
#define ZT_OFF     958464u      // float[8*4096*384]   50331648

// 64-bit DPP move (per-half), old=0 identity for nonneg max keys.
// Sequence validated on HW in round 5 (bit-exact FPS indices).
template<int CTRL, int RM>
__device__ __forceinline__ unsigned long long dpp_mov64(unsigned long long k) {
    int tlo = __builtin_amdgcn_update_dpp(0, (int)(unsigned)(k & 0xffffffffull),
                                          CTRL, RM, 0xf, false);
    int thi = __builtin_amdgcn_update_dpp(0, (int)(unsigned)(k >> 32),
                                          CTRL, RM, 0xf, false);
    return ((unsigned long long)(unsigned)thi << 32) | (unsigned)tlo;
}

// ---------------------------------------------------------------------------
// Launch 1: blocks 0..7 = FPS (one per batch); blocks 8..79 = prep.
// FPS: 512 threads (2 waves/SIMD for stall hiding), 8 pts/thread in regs.
// Exact reference arithmetic: ((dx*dx+dy*dy)+dz*dz) via _rn intrinsics.
// Argmax key = (f32bits(mind)<<32) | (4095-j): max == largest dist, first
// index on ties (np.argmax). Winner coords travel with the key through LDS
// (single LDS round per iteration). Writes new_p into d_out[0..24576).
// ---------------------------------------------------------------------------
__global__ __launch_bounds__(512) void fps_prep_kernel(
        const float* __restrict__ p,
        const float* __restrict__ Wt, const float* __restrict__ gt,
        const float* __restrict__ bt, const float* __restrict__ mt,
        const float* __restrict__ vt, const float* __restrict__ Wc,
        const float* __restrict__ gc, const float* __restrict__ bc,
        const float* __restrict__ mc, const float* __restrict__ vc,
        float* __restrict__ Ws, float* __restrict__ beta1,
        float* __restrict__ WcT, float* __restrict__ beta2,
        int* __restrict__ samp, float* __restrict__ out) {
    if (blockIdx.x >= BB) {
        // ---- prep: fold BN scale into weights (72 blocks x 512 = 36864) ----
        int i = (blockIdx.x - BB) * 512 + threadIdx.x;
        if (i < C2) {
            float s1 = gt[i] / sqrtf(vt[i] + 1e-5f);
            beta1[i] = bt[i] - mt[i] * s1;
            float s2 = gc[i] / sqrtf(vc[i] + 1e-5f);
            beta2[i] = bc[i] - mc[i] * s2;
        }
        if (i < 384 * 96) {
            int r = i / 96, c = i - r * 96;
            int o = (r < C2) ? r : r - C2;
            float s1 = gt[o] / sqrtf(vt[o] + 1e-5f);
            float w = (r < C2) ? Wt[o * C2 + c] : Wt[o * C2 + 96 + c];
            Ws[i] = w * s1;
        }
        if (i < C2 * C2) {
            int o = i / C2, c = i - o * C2;
            float s2 = gc[o] / sqrtf(vc[o] + 1e-5f);
            WcT[c * C2 + o] = Wc[i] * s2;
        }
        return;
    }
    // ---- FPS ----
    int b = blockIdx.x;
    const float* pb = p + (size_t)b * NN * 3;
    __shared__ unsigned long long redk[2][8];
    __shared__ float4 redc[2][8];
    int tid = threadIdx.x;
    int jbase = tid * FPT;

    // load 24 contiguous floats (8 points) per thread into registers
    float c24[24];
    const float4* pb4 = (const float4*)(pb + (size_t)jbase * 3);
    #pragma unroll
    for (int i = 0; i < 6; ++i) ((float4*)c24)[i] = pb4[i];
    float px[FPT], py[FPT], pz[FPT], mind[FPT];
    #pragma unroll
    for (int i = 0; i < FPT; ++i) {
        px[i] = c24[3*i+0]; py[i] = c24[3*i+1]; pz[i] = c24[3*i+2];
        mind[i] = 1e10f;
    }

    int last = 0;
    float lx = pb[0], ly = pb[1], lz = pb[2];
    unsigned inv_base = 4095u - (unsigned)jbase;

    for (int it = 0; it < NP; ++it) {
        if (tid == 0) {
            samp[b * NP + it] = last;
            size_t o3 = ((size_t)b * NP + it) * 3;
            out[o3 + 0] = lx; out[o3 + 1] = ly; out[o3 + 2] = lz;
        }
        // exact-scan distance update
        float m[FPT];
        #pragma unroll
        for (int i = 0; i < FPT; ++i) {
            float dx = __fsub_rn(px[i], lx);
            float dy = __fsub_rn(py[i], ly);
            float dz = __fsub_rn(pz[i], lz);
            float d = __fadd_rn(__fadd_rn(__fmul_rn(dx, dx), __fmul_rn(dy, dy)),
                                __fmul_rn(dz, dz));
            float mi = fminf(mind[i], d);
            mind[i] = mi;
            m[i] = mi;
        }
        // tournament argmax over 8 (strict > keeps lower index on ties)
        float v4[4]; int i4v[4];
        #pragma unroll
        for (int q = 0; q < 4; ++q) {
            bool t = m[2*q+1] > m[2*q];
            v4[q] = t ? m[2*q+1] : m[2*q];
            i4v[q] = t ? 2*q+1 : 2*q;
        }
        float v2a[2]; int i2v[2];
        #pragma unroll
        for (int q = 0; q < 2; ++q) {
            bool t = v4[2*q+1] > v4[2*q];
            v2a[q] = t ? v4[2*q+1] : v4[2*q];
            i2v[q] = t ? i4v[2*q+1] : i4v[2*q];
        }
        bool tf = v2a[1] > v2a[0];
        float bv = tf ? v2a[1] : v2a[0];
        int ii  = tf ? i2v[1] : i2v[0];
        unsigned long long key =
            ((unsigned long long)__float_as_uint(bv) << 32)
            | (unsigned long long)(inv_base - (unsigned)ii);

        // wave64 max-reduce via DPP; total lands in lane 63
        unsigned long long red = key, t;
        t = dpp_mov64<0x111, 0xf>(red); red = (t > red) ? t : red;  // row_shr:1
        t = dpp_mov64<0x112, 0xf>(red); red = (t > red) ? t : red;  // row_shr:2
        t = dpp_mov64<0x114, 0xf>(red); red = (t > red) ? t : red;  // row_shr:4
        t = dpp_mov64<0x118, 0xf>(red); red = (t > red) ? t : red;  // row_shr:8
        t = dpp_mov64<0x142, 0xa>(red); red = (t > red) ? t : red;  // row_bcast:15
        t = dpp_mov64<0x143, 0xc>(red); red = (t > red) ? t : red;  // row_bcast:31

        // broadcast lane-63 total; the unique winning lane writes key+coords
        unsigned rlo = (unsigned)__builtin_amdgcn_readlane((int)(unsigned)(red & 0xffffffffull), 63);
        unsigned rhi = (unsigned)__builtin_amdgcn_readlane((int)(unsigned)(red >> 32), 63);
        unsigned long long wkey = ((unsigned long long)rhi << 32) | rlo;
        int buf = it & 1;
        if (key == wkey) {          // keys globally unique (index in low bits)
            int wv = tid >> 6;
            redk[buf][wv] = wkey;
            redc[buf][wv] = make_float4(px[ii], py[ii], pz[ii], 0.0f);
        }
        __syncthreads();

        // single LDS round: read all 8 (key,coord) tuples, static tree merge
        unsigned long long k0 = redk[buf][0], k1 = redk[buf][1];
        unsigned long long k2 = redk[buf][2], k3 = redk[buf][3];
        unsigned long long k4 = redk[buf][4], k5 = redk[buf][5];
        unsigned long long k6 = redk[buf][6], k7 = redk[buf][7];
        float4 c0 = redc[buf][0], c1 = redc[buf][1];
        float4 c2 = redc[buf][2], c3 = redc[buf][3];
        float4 c4 = redc[buf][4], c5 = redc[buf][5];
        float4 c6 = redc[buf][6], c7 = redc[buf][7];
        #define MRG(ka, ca, kb, cb) { bool tm = (kb) > (ka); \
            ka = tm ? (kb) : (ka); \
            ca.x = tm ? cb.x : ca.x; ca.y = tm ? cb.y : ca.y; ca.z = tm ? cb.z : ca.z; }
        MRG(k0, c0, k1, c1); MRG(k2, c2, k3, c3);
        MRG(k4, c4, k5, c5); MRG(k6, c6, k7, c7);
        MRG(k0, c0, k2, c2); MRG(k4, c4, k6, c6);
        MRG(k0, c0, k4, c4);
        #undef MRG
        last = 4095 - (int)(unsigned)(k0 & 0xffffffffull);
        lx = c0.x; ly = c0.y; lz = c0.z;
        // redk/redc double-buffered: next write to this buf is 2 barriers away
    }
}

// ---------------------------------------------------------------------------
// Launch 2: blocks 0..2047 = ball query; blocks 2048..5119 = GEMM1.
// Shared LDS aliased through one array (ballquery 12288 floats, gemm 12352).
// ---------------------------------------------------------------------------
__global__ __launch_bounds__(256) void bq_gemm_kernel(
        const float* __restrict__ p, const float* __restrict__ newp,
        int* __restrict__ nbr,
        const float* __restrict__ x, const float* __restrict__ Ws,
        float* __restrict__ zt) {
    __shared__ float smem[12352];
    int tid = threadIdx.x;

    if (blockIdx.x < 2048) {
        // ---- ball query: one wave per center ----
        float* sx = smem;
        float* sy = smem + NN;
        float* sz = smem + 2 * NN;
        int blk = blockIdx.x;
        int b = blk >> 8;
        const float* pb = p + (size_t)b * NN * 3;
        for (int idx = tid; idx < NN; idx += 256) {
            sx[idx] = pb[idx * 3 + 0];
            sy[idx] = pb[idx * 3 + 1];
            sz[idx] = pb[idx * 3 + 2];
        }
        __syncthreads();
        int wave = tid >> 6, lane = tid & 63;
        int g = (blk & 255) * 4 + wave;    // 0..1023
        int gidx = b * NP + g;
        float cx = newp[(size_t)gidx * 3 + 0];
        float cy = newp[(size_t)gidx * 3 + 1];
        float cz = newp[(size_t)gidx * 3 + 2];
        const float R2 = 0.01f;
        int cnt = 0, first = -1;
        for (int chunk = 0; chunk < NN / 64 && cnt < NS; ++chunk) {
            int j = chunk * 64 + lane;
            float dx = __fsub_rn(cx, sx[j]);
            float dy = __fsub_rn(cy, sy[j]);
            float dz = __fsub_rn(cz, sz[j]);
            float d2 = __fadd_rn(__fadd_rn(__fmul_rn(dx, dx), __fmul_rn(dy, dy)),
                                 __fmul_rn(dz, dz));
            unsigned long long mask = __ballot(d2 < R2);
            while (mask && cnt < NS) {
                int bit = __ffsll(mask) - 1;
                mask &= mask - 1;
                int idx = chunk * 64 + bit;
                if (first < 0) first = idx;
                if (lane == 0) nbr[(size_t)gidx * NS + cnt] = idx;
                ++cnt;
            }
        }
        if (lane == 0) {
            for (int i = cnt; i < NS; ++i) nbr[(size_t)gidx * NS + i] = first;
        }
    } else {
        // ---- GEMM1: zt[b][j][384] = Ws[384x96] @ relu(x[b][:, j]) ----
        float* xt = smem;            // [96][64]
        float* wt = smem + 6144;     // [64][97]
        int g = blockIdx.x - 2048;
        int b = g & 7;
        int t2 = g >> 3;             // 0..383
        int ob = t2 >> 6;            // 0..5
        int jt = t2 & 63;            // 0..63

        for (int idx = tid; idx < 96 * 64; idx += 256) {
            int c = idx >> 6, j = idx & 63;
            xt[c * 64 + j] = fmaxf(x[((size_t)b * CC + c) * NN + jt * 64 + j], 0.0f);
        }
        for (int idx = tid; idx < 64 * 96; idx += 256) {
            int r = idx / 96, c = idx - r * 96;
            wt[r * 97 + c] = Ws[(ob * 64 + r) * 96 + c];
        }
        __syncthreads();

        int ty = tid >> 4, tx = tid & 15;
        float acc[4][4] = {};
        for (int k = 0; k < 96; ++k) {
            float a0 = wt[(ty * 4 + 0) * 97 + k];
            float a1 = wt[(ty * 4 + 1) * 97 + k];
            float a2 = wt[(ty * 4 + 2) * 97 + k];
            float a3 = wt[(ty * 4 + 3) * 97 + k];
            float4 bv = *(const float4*)&xt[k * 64 + tx * 4];
            acc[0][0] = fmaf(a0, bv.x, acc[0][0]); acc[0][1] = fmaf(a0, bv.y, acc[0][1]);
            acc[0][2] = fmaf(a0, bv.z, acc[0][2]); acc[0][3] = fmaf(a0, bv.w, acc[0][3]);
            acc[1][0] = fmaf(a1, bv.x, acc[1][0]); acc[1][1] = fmaf(a1, bv.y, acc[1][1]);
            acc[1][2] = fmaf(a1, bv.z, acc[1][2]); acc[1][3] = fmaf(a1, bv.w, acc[1][3]);
            acc[2][0] = fmaf(a2, bv.x, acc[2][0]); acc[2][1] = fmaf(a2, bv.y, acc[2][1]);
            acc[2][2] = fmaf(a2, bv.z, acc[2][2]); acc[2][3] = fmaf(a2, bv.w, acc[2][3]);
            acc[3][0] = fmaf(a3, bv.x, acc[3][0]); acc[3][1] = fmaf(a3, bv.y, acc[3][1]);
            acc[3][2] = fmaf(a3, bv.z, acc[3][2]); acc[3][3] = fmaf(a3, bv.w, acc[3][3]);
        }
        for (int jj = 0; jj < 4; ++jj) {
            int j = jt * 64 + tx * 4 + jj;
            float4 v = make_float4(acc[0][jj], acc[1][jj], acc[2][jj], acc[3][jj]);
            *(float4*)&zt[((size_t)b * NN + j) * 384 + ob * 64 + ty * 4] = v;
        }
    }
}

// ---------------------------------------------------------------------------
// Fused: gather zc+zn, +beta -> relu, sin/cos pos embed, agg=(t+1)*emb,
// max+mean pool, relu, 192x192 conv2 (BN folded) -> relu -> f32 store.
// ---------------------------------------------------------------------------
__global__ __launch_bounds__(192) void fused_kernel(const float* __restrict__ p,
                                                    const float* __restrict__ newp,
                                                    const int* __restrict__ samp,
                                                    const int* __restrict__ nbr,
                                                    const float* __restrict__ zt,
                                                    const float* __restrict__ beta1,
                                                    const float* __restrict__ WcT,
                                                    const float* __restrict__ beta2,
                                                    float* __restrict__ out) {
    int blk = blockIdx.x;
    int b = blk >> 10, g = blk & 1023;
    int tid = threadIdx.x;
    __shared__ float dp[3][NS];
    __shared__ int nb[NS];
    __shared__ float pl[C2];

    if (tid < NS) {
        int j = nbr[(size_t)blk * NS + tid];
        nb[tid] = j;
        dp[0][tid] = p[((size_t)b * NN + j) * 3 + 0] - newp[(size_t)blk * 3 + 0];
        dp[1][tid] = p[((size_t)b * NN + j) * 3 + 1] - newp[(size_t)blk * 3 + 1];
        dp[2][tid] = p[((size_t)b * NN + j) * 3 + 2] - newp[(size_t)blk * 3 + 2];
    }
    __syncthreads();

    int o = tid;
    int sidx = samp[blk];
    float zc = zt[((size_t)b * NN + sidx) * 384 + o];
    float bet = beta1[o];
    int axis = o >> 6;        // 0..2
    int k = o & 63;
    int kk = (k < 32) ? k : k - 32;
    float dim = powf(500.0f, (float)kk * (1.0f / 32.0f));

    float mx = -3.4e38f, sm = 0.0f;
    for (int s = 0; s < NS; ++s) {
        float zn = zt[((size_t)b * NN + nb[s]) * 384 + C2 + o];
        float t = fmaxf(zc + zn + bet, 0.0f);
        float pos = (50.0f * dp[axis][s]) / dim;
        float e = (k < 32) ? sinf(pos) : cosf(pos);
        float a = fmaf(t, e, e);          // xj*emb + emb
        mx = fmaxf(mx, a);
        sm += a;
    }
    pl[o] = fmaxf(mx + sm * (1.0f / 16.0f), 0.0f);
    __syncthreads();

    float acc = 0.0f;
    for (int c = 0; c < C2; ++c) acc = fmaf(WcT[c * C2 + o], pl[c], acc);
    float res = fmaxf(acc + beta2[o], 0.0f);
    out[BB * NP * 3 + ((size_t)b * C2 + o) * NP + g] = res;
}

// ---------------------------------------------------------------------------
extern "C" void kernel_launch(void* const* d_in, const int* in_sizes, int n_in,
                              void* d_out, int out_size, void* d_ws, size_t ws_size,
                              hipStream_t stream) {
    (void)in_sizes; (void)n_in; (void)out_size; (void)ws_size;
    const float* p  = (const float*)d_in[0];
    const float* x  = (const float*)d_in[1];
    const float* Wt = (const float*)d_in[2];
    const float* gt = (const float*)d_in[3];
    const float* bt = (const float*)d_in[4];
    const float* mt = (const float*)d_in[5];
    const float* vt = (const float*)d_in[6];
    const float* Wc = (const float*)d_in[7];
    const float* gc = (const float*)d_in[8];
    const float* bc = (const float*)d_in[9];
    const float* mc = (const float*)d_in[10];
    const float* vc = (const float*)d_in[11];
    float* out = (float*)d_out;              // f32 output (reference is all-f32)
    char* ws = (char*)d_ws;

    int*   samp  = (int*)(ws + SAMP_OFF);
    int*   nbr   = (int*)(ws + NBR_OFF);
    float* Ws    = (float*)(ws + WSW_OFF);
    float* beta1 = (float*)(ws + B1_OFF);
    float* WcT   = (float*)(ws + WCT_OFF);
    float* beta2 = (float*)(ws + B2_OFF);
    float* zt    = (float*)(ws + ZT_OFF);
    const float* newp = out;                 // new_p lives in d_out[0 .. 24576)

    fps_prep_kernel<<<dim3(BB + 72), dim3(512), 0, stream>>>(
        p, Wt, gt, bt, mt, vt, Wc, gc, bc, mc, vc,
        Ws, beta1, WcT, beta2, samp, out);
    bq_gemm_kernel<<<dim3(2048 + 3072), dim3(256), 0, stream>>>(
        p, newp, nbr, x, Ws, zt);
    fused_kernel<<<dim3(BB * NP), dim3(192), 0, stream>>>(
        p, newp, samp, nbr, zt, beta1, WcT, beta2, out);
}